// Round 14
// baseline (108.177 us; speedup 1.0000x reference)
//
#include <hip/hip_runtime.h>

// ---------------- constants ----------------
#define HEADS 8
#define DH 40
constexpr int Bn   = 8;
constexpr int Cc   = 320;
constexpr int Nn   = 4096;        // tokens per batch (64*64)
constexpr int CTX  = 77;
constexpr float LN_EPS = 1e-5f;
constexpr float SCALE  = 0.15811388300841897f; // 40^-0.5

typedef short bf16x8 __attribute__((ext_vector_type(8)));
typedef float f32x4  __attribute__((ext_vector_type(4)));
typedef unsigned short us;

__device__ inline us f2bf(float f) {
    unsigned u = __float_as_uint(f);
    u += 0x7fffu + ((u >> 16) & 1u);
    return (us)(u >> 16);
}
__device__ inline float bf2f(us h) {
    return __uint_as_float(((unsigned)h) << 16);
}

// ---------------- weight prep: transposes (Wk,Wv,Wout) + Wq B-frag pack, one launch ----------------
__global__ __launch_bounds__(256) void wtrans_all(const float* __restrict__ Wq,
                                                  const float* __restrict__ Wk,
                                                  const float* __restrict__ Wv,
                                                  const float* __restrict__ Wout,
                                                  us* __restrict__ wqF,
                                                  us* __restrict__ WkT,
                                                  us* __restrict__ WvT,
                                                  us* __restrict__ WoutT) {
    int id = blockIdx.x;
    if (id >= 580) {
        // Wq -> MFMA B-fragment order: wqF[(ct*10+kc)][lane] = Wq[kc*32+g*8+e][ct*16+lr]
        int wid = (id - 580) * 4 + (threadIdx.x >> 6);  // 0..199
        int lane = threadIdx.x & 63, lr = lane & 15, g = lane >> 4;
        int ct = wid / 10, kc = wid % 10;
        int k0 = kc * 32 + g * 8, co = ct * 16 + lr;
        us tmp[8];
        #pragma unroll
        for (int e = 0; e < 8; ++e)
            tmp[e] = f2bf(Wq[(size_t)(k0 + e) * 320 + co]);
        ((uint4*)wqF)[(size_t)wid * 64 + lane] = *(uint4*)tmp;
        return;
    }
    const float* in; us* out; int K, t;
    if (id < 240)      { in = Wk;   out = WkT;   K = 768; t = id; }
    else if (id < 480) { in = Wv;   out = WvT;   K = 768; t = id - 240; }
    else               { in = Wout; out = WoutT; K = 320; t = id - 480; }
    int ktiles = K >> 5;
    int kb = (t % ktiles) * 32, ob = (t / ktiles) * 32;

    __shared__ float tile[32][33];
    int tx = threadIdx.x & 31, ty = threadIdx.x >> 5; // ty 0..7
    #pragma unroll
    for (int i = 0; i < 32; i += 8)
        tile[ty + i][tx] = in[(size_t)(kb + ty + i) * 320 + ob + tx];
    __syncthreads();
    #pragma unroll
    for (int i = 0; i < 32; i += 8)
        out[(size_t)(ob + ty + i) * K + kb + tx] = f2bf(tile[tx][ty + i]);
}

// ---------------- fused LayerNorm + Q projection -> qG (dense fragment order) ----------------
__global__ __launch_bounds__(256, 3) void ln_q_fused(const float* __restrict__ x,
                                                     const float* __restrict__ gamma,
                                                     const float* __restrict__ beta,
                                                     const us* __restrict__ wqF,
                                                     us* __restrict__ qG) {
    __shared__ __align__(16) us xnt[64 * 328];
    __shared__ float red1[4][64], red2[4][64];
    __shared__ float mu_s[64], rs_s[64];

    int b  = blockIdx.x >> 6;
    int t0 = (blockIdx.x & 63) * 64;
    int tid = threadIdx.x;
    int tl = tid & 63, cg = tid >> 6;
    const float* xb = x + (size_t)b * Cc * Nn + t0 + tl;

    float s1 = 0.f, s2 = 0.f;
    #pragma unroll 8
    for (int i = 0; i < 80; ++i) {
        int c = cg * 80 + i;
        float v = xb[(size_t)c * Nn];
        s1 += v; s2 += v * v;
        xnt[tl * 328 + c] = f2bf(v);
    }
    red1[cg][tl] = s1; red2[cg][tl] = s2;
    __syncthreads();
    if (tid < 64) {
        float a1 = red1[0][tl] + red1[1][tl] + red1[2][tl] + red1[3][tl];
        float a2 = red2[0][tl] + red2[1][tl] + red2[2][tl] + red2[3][tl];
        float mu = a1 * (1.0f / Cc);
        float var = a2 * (1.0f / Cc) - mu * mu;
        mu_s[tl] = mu; rs_s[tl] = rsqrtf(var + LN_EPS);
    }
    __syncthreads();
    float mu = mu_s[tl], rs = rs_s[tl];
    #pragma unroll 4
    for (int i = 0; i < 40; ++i) {
        int c = cg * 80 + i * 2;
        unsigned u = *(unsigned*)&xnt[tl * 328 + c];
        float v0 = bf2f((us)(u & 0xffff));
        float v1 = bf2f((us)(u >> 16));
        unsigned lo = f2bf((v0 - mu) * rs * gamma[c]     + beta[c]);
        unsigned hi = f2bf((v1 - mu) * rs * gamma[c + 1] + beta[c + 1]);
        *(unsigned*)&xnt[tl * 328 + c] = lo | (hi << 16);
    }
    __syncthreads();

    int lane = tid & 63, w = tid >> 6;
    int lr = lane & 15, g = lane >> 4;
    f32x4 acc[4][5] = {};   // [token-tile][out-tile]
    const bf16x8* wq = (const bf16x8*)wqF;
    for (int kc = 0; kc < 10; ++kc) {
        bf16x8 bfr[5];
        #pragma unroll
        for (int nt = 0; nt < 5; ++nt)
            bfr[nt] = wq[(size_t)((w * 5 + nt) * 10 + kc) * 64 + lane];
        bf16x8 afr[4];
        #pragma unroll
        for (int mt = 0; mt < 4; ++mt)
            afr[mt] = *(const bf16x8*)&xnt[(mt * 16 + lr) * 328 + kc * 32 + g * 8];
        #pragma unroll
        for (int mt = 0; mt < 4; ++mt)
            #pragma unroll
            for (int nt = 0; nt < 5; ++nt)
                acc[mt][nt] = __builtin_amdgcn_mfma_f32_16x16x32_bf16(afr[mt], bfr[nt], acc[mt][nt], 0, 0, 0);
    }
    __syncthreads();   // xnt consumed; reuse as q-tile [64 tok][320 co]

    #pragma unroll
    for (int mt = 0; mt < 4; ++mt)
        #pragma unroll
        for (int nt = 0; nt < 5; ++nt)
            #pragma unroll
            for (int r = 0; r < 4; ++r)
                xnt[(mt * 16 + g * 4 + r) * 328 + w * 80 + nt * 16 + lr] = f2bf(acc[mt][nt][r]);
    __syncthreads();

    // emit 40 dense fragment blobs (4 tiles x 10 k-frags), 16B/lane coalesced
    size_t gtb = (size_t)b * 256 + (blockIdx.x & 63) * 4;
    #pragma unroll
    for (int it = 0; it < 10; ++it) {
        int f_lin = it * 4 + w;            // 0..39
        int tile = f_lin / 10, f = f_lin % 10;
        uint4 v = *(uint4*)&xnt[(tile * 16 + lr) * 328 + f * 32 + g * 8];
        ((uint4*)qG)[((gtb + tile) * 10 + f) * 64 + lane] = v;
    }
}

// ---------------- K/V projection: ctx fp32 [616][768] x W^T -> bf16 [616][320] ----------------
__global__ __launch_bounds__(256) void gemm_kv(const float* __restrict__ ctx,
                                               const us* __restrict__ WkT,
                                               const us* __restrict__ WvT,
                                               us* __restrict__ kbuf,
                                               us* __restrict__ vbuf) {
    const us* Bt = blockIdx.z ? WvT : WkT;
    us* Cm = blockIdx.z ? vbuf : kbuf;
    constexpr int K = 768, M = 616;
    __shared__ __align__(16) char Al[64 * 128];
    __shared__ __align__(16) char Bl[64 * 128];
    int m0 = blockIdx.x * 64;
    int n0 = blockIdx.y * 64;
    int tid = threadIdx.x;
    int lane = tid & 63, wave = tid >> 6;
    int wm = (wave >> 1) * 32, wn = (wave & 1) * 32;

    f32x4 acc[2][2] = {};

    for (int kc = 0; kc < K; kc += 64) {
        #pragma unroll
        for (int i = 0; i < 2; ++i) {
            int chunk = tid + 256 * i;
            int r = chunk >> 3, c8 = chunk & 7;
            int off = (r * 128 + c8 * 16) ^ ((r & 7) << 4);
            int gr = m0 + r;
            uint4 av = make_uint4(0, 0, 0, 0);
            if (gr < M) {
                float4 f0 = *(const float4*)(ctx + (size_t)gr * K + kc + c8 * 8);
                float4 f1 = *(const float4*)(ctx + (size_t)gr * K + kc + c8 * 8 + 4);
                av.x = f2bf(f0.x) | ((unsigned)f2bf(f0.y) << 16);
                av.y = f2bf(f0.z) | ((unsigned)f2bf(f0.w) << 16);
                av.z = f2bf(f1.x) | ((unsigned)f2bf(f1.y) << 16);
                av.w = f2bf(f1.z) | ((unsigned)f2bf(f1.w) << 16);
            }
            *(uint4*)(Al + off) = av;
            *(uint4*)(Bl + off) = *(const uint4*)(Bt + (size_t)(n0 + r) * K + kc + c8 * 8);
        }
        __syncthreads();

        #pragma unroll
        for (int kk = 0; kk < 64; kk += 32) {
            bf16x8 a[2], bfr[2];
            int lr = lane & 15;
            int lkb = (kk + (lane >> 4) * 8) * 2;
            #pragma unroll
            for (int mi = 0; mi < 2; ++mi) {
                int row = wm + mi * 16 + lr;
                a[mi] = *(const bf16x8*)(Al + ((row * 128 + lkb) ^ ((row & 7) << 4)));
            }
            #pragma unroll
            for (int ni = 0; ni < 2; ++ni) {
                int row = wn + ni * 16 + lr;
                bfr[ni] = *(const bf16x8*)(Bl + ((row * 128 + lkb) ^ ((row & 7) << 4)));
            }
            #pragma unroll
            for (int mi = 0; mi < 2; ++mi)
                #pragma unroll
                for (int ni = 0; ni < 2; ++ni)
                    acc[mi][ni] = __builtin_amdgcn_mfma_f32_16x16x32_bf16(a[mi], bfr[ni], acc[mi][ni], 0, 0, 0);
        }
        __syncthreads();
    }

    int lr = lane & 15, lq = lane >> 4;
    #pragma unroll
    for (int mi = 0; mi < 2; ++mi)
        #pragma unroll
        for (int ni = 0; ni < 2; ++ni)
            #pragma unroll
            for (int r = 0; r < 4; ++r) {
                int row = m0 + wm + mi * 16 + lq * 4 + r;
                int col = n0 + wn + ni * 16 + lr;
                if (row < M)
                    Cm[(size_t)row * 320 + col] = f2bf(acc[mi][ni][r]);
            }
}

// ---------------- VW precompute: vwT[b][c][h*80+j] = sum_d Wout[h*40+d][c] * V[b,j,h*40+d] ----------------
__global__ __launch_bounds__(256) void gemm_vw(const us* __restrict__ WoutT,
                                               const us* __restrict__ vbuf,
                                               us* __restrict__ vwT) {
    int b = blockIdx.z, h = blockIdx.y, cb = blockIdx.x * 64;
    int tid = threadIdx.x, lane = tid & 63, w = tid >> 6;
    int lr = lane & 15, g = lane >> 4;

    int crow = cb + w * 16 + lr;
    const us* ab = WoutT + (size_t)crow * 320 + h * DH;
    bf16x8 a0 = *(const bf16x8*)(ab + g * 8);
    bf16x8 a1 = {};
    if (g == 0) a1 = *(const bf16x8*)(ab + 32);

    f32x4 acc[5] = {};
    #pragma unroll
    for (int nt = 0; nt < 5; ++nt) {
        int j = nt * 16 + lr;
        bool jv = j < CTX;
        const us* kr = vbuf + (size_t)(b * CTX + (jv ? j : 0)) * 320 + h * DH;
        bf16x8 b0 = {}, b1 = {};
        if (jv) b0 = *(const bf16x8*)(kr + g * 8);
        if (jv && g == 0) b1 = *(const bf16x8*)(kr + 32);
        acc[nt] = __builtin_amdgcn_mfma_f32_16x16x32_bf16(a0, b0, acc[nt], 0, 0, 0);
        acc[nt] = __builtin_amdgcn_mfma_f32_16x16x32_bf16(a1, b1, acc[nt], 0, 0, 0);
    }

    #pragma unroll
    for (int nt = 0; nt < 5; ++nt)
        #pragma unroll
        for (int r = 0; r < 4; ++r) {
            int c = cb + w * 16 + g * 4 + r;
            float val = (nt == 4 && lr >= 13) ? 0.f : acc[nt][r];
            vwT[((size_t)(b * 320 + c)) * 640 + h * 80 + nt * 16 + lr] = f2bf(val);
        }
}

// ---------------- repack K + VW into MFMA-fragment order, one launch ----------------
__global__ __launch_bounds__(256) void repack_all(const us* __restrict__ kbuf,
                                                  const us* __restrict__ vwT,
                                                  us* __restrict__ kF,
                                                  us* __restrict__ vwF) {
    int id = blockIdx.x;
    int lane = threadIdx.x & 63, lr = lane & 15, g = lane >> 4;
    if (id < 160) {
        int wid = id * 4 + (threadIdx.x >> 6);       // 0..639
        int kc = wid & 1, nt = (wid >> 1) % 5, h = (wid / 10) & 7, b = wid / 80;
        int j = nt * 16 + lr, d0 = kc * 32 + g * 8;
        bf16x8 v = {};
        if (j < CTX && d0 < DH)
            v = *(const bf16x8*)(kbuf + ((size_t)(b * CTX + j)) * 320 + h * DH + d0);
        ((bf16x8*)kF)[(size_t)wid * 64 + lane] = v;
    } else {
        int wid = (id - 160) * 4 + (threadIdx.x >> 6);   // 0..3199
        int mi = wid % 5, ks = (wid / 5) % 20, w = (wid / 100) & 3, b = wid / 400;
        int co = w * 80 + mi * 16 + lr, k = ks * 32 + g * 8;
        bf16x8 v = *(const bf16x8*)(vwT + ((size_t)(b * 320 + co)) * 640 + k);
        ((bf16x8*)vwF)[(size_t)wid * 64 + lane] = v;
    }
}

// ---------------- fused attention + out-proj: 512 threads, 64 tokens/block, K-split PV ----------------
// 512 blocks (b = bid&7 XCD-local). Phase A: wave=head -> P[64][640] LDS (80 KB).
// Phase B: wave=(co-slice wc, K-half kh) -> o[5][4] over K=320; each vwF byte read
// ONCE per block. Phase C: exchange partials via freed P buffer.
// RULE #20: every index into o[][] is compile-time constant (kh-select on VALUES).
__global__ __launch_bounds__(512, 2) void attn_out(const us* __restrict__ qG,
                                                   const us* __restrict__ kF,
                                                   const us* __restrict__ vwF,
                                                   const float* __restrict__ bout,
                                                   const float* __restrict__ x,
                                                   float* __restrict__ out) {
    __shared__ __align__(16) char smem[81920];   // P [64][640] bf16 swz | f32x4 partial buf

    int bid = blockIdx.x;
    int b = bid & 7, ts = bid >> 3;       // XCD-local batch; ts 0..63
    int t0 = ts * 64;
    int tid = threadIdx.x, lane = tid & 63, w = tid >> 6;   // w 0..7
    int lr = lane & 15, g = lane >> 4;

    const bf16x8* qfb = (const bf16x8*)qG;
    const bf16x8* kfb = (const bf16x8*)kF;
    char* Pl = smem;

    // ---- phase A: QK^T + softmax. wave w = head w, 4 token-16-tiles ----
    {
        int h = w;
        size_t kfh = (size_t)((b * 8 + h) * 10) * 64;
        bf16x8 kb0[5], kb1[5];
        #pragma unroll
        for (int nt = 0; nt < 5; ++nt) {
            kb0[nt] = kfb[kfh + (nt * 2 + 0) * 64 + lane];
            kb1[nt] = kfb[kfh + (nt * 2 + 1) * 64 + lane];
        }
        // dense qG gather: k = 40h + 8g + e  ->  frag (5h+g)>>2, lane ((5h+g)&3)*16+lr
        int f0 = (5 * h + g) >> 2, l0 = ((5 * h + g) & 3) * 16 + lr;
        int f1 = (5 * h + 4) >> 2, l1 = ((5 * h + 4) & 3) * 16 + lr;

        #pragma unroll
        for (int mt = 0; mt < 4; ++mt) {
            const bf16x8* qt = qfb + (size_t)(b * 256 + ts * 4 + mt) * 640;
            bf16x8 a0 = qt[f0 * 64 + l0];
            bf16x8 a1 = {};
            if (g == 0) a1 = qt[f1 * 64 + l1];

            f32x4 S[5] = {};
            #pragma unroll
            for (int nt = 0; nt < 5; ++nt) {
                S[nt] = __builtin_amdgcn_mfma_f32_16x16x32_bf16(a0, kb0[nt], S[nt], 0, 0, 0);
                S[nt] = __builtin_amdgcn_mfma_f32_16x16x32_bf16(a1, kb1[nt], S[nt], 0, 0, 0);
            }

            float pv[5][4];
            #pragma unroll
            for (int nt = 0; nt < 5; ++nt)
                #pragma unroll
                for (int r = 0; r < 4; ++r)
                    pv[nt][r] = (nt == 4 && lr >= 13) ? 0.f : __expf(S[nt][r] * SCALE);
            #pragma unroll
            for (int r = 0; r < 4; ++r) {
                float su = pv[0][r] + pv[1][r] + pv[2][r] + pv[3][r] + pv[4][r];
                #pragma unroll
                for (int off = 1; off < 16; off <<= 1)
                    su += __shfl_xor(su, off);
                float inv = 1.0f / su;
                int row = mt * 16 + g * 4 + r;
                #pragma unroll
                for (int nt = 0; nt < 5; ++nt)
                    *(us*)(Pl + ((row * 1280 + (h * 80 + nt * 16 + lr) * 2) ^ ((row & 7) << 4))) =
                        f2bf(pv[nt][r] * inv);
            }
        }
    }
    __syncthreads();

    // ---- phase B: PV, K-split. wave -> (wc = co-slice, kh = K-half) ----
    int wc = w >> 1, kh = w & 1;
    f32x4 o[5][4] = {};   // ONLY static indices below (rule #20)
    const bf16x8* vwb = (const bf16x8*)vwF + (size_t)((b * 4 + wc) * 100 + kh * 50) * 64 + lane;
    __builtin_amdgcn_s_setprio(1);
    for (int ks = 0; ks < 10; ++ks) {
        bf16x8 pb[4];
        #pragma unroll
        for (int nt = 0; nt < 4; ++nt) {
            int row = nt * 16 + lr;
            pb[nt] = *(const bf16x8*)(Pl + ((row * 1280 + (kh * 10 + ks) * 64 + g * 16) ^ ((row & 7) << 4)));
        }
        #pragma unroll
        for (int mi = 0; mi < 5; ++mi) {
            bf16x8 av = vwb[(ks * 5 + mi) * 64];
            #pragma unroll
            for (int nt = 0; nt < 4; ++nt)
                o[mi][nt] = __builtin_amdgcn_mfma_f32_16x16x32_bf16(av, pb[nt], o[mi][nt], 0, 0, 0);
        }
    }
    __builtin_amdgcn_s_setprio(0);
    __syncthreads();   // P consumed; smem becomes the partial-sum buffer

    // ---- phase C: cross-K reduction via LDS (static o-indices; kh selects VALUES) ----
    bool hi = (kh != 0);
    f32x4* part = (f32x4*)smem;
    #pragma unroll
    for (int mi = 0; mi < 5; ++mi) {
        // write the NON-owned token-half partials
        f32x4 p0 = hi ? o[mi][0] : o[mi][2];
        f32x4 p1 = hi ? o[mi][1] : o[mi][3];
        part[((wc * 2 + kh) * 10 + mi * 2 + 0) * 64 + lane] = p0;
        part[((wc * 2 + kh) * 10 + mi * 2 + 1) * 64 + lane] = p1;
    }
    __syncthreads();
    int oth = 1 - kh;
    #pragma unroll
    for (int mi = 0; mi < 5; ++mi) {
        f32x4 q0 = part[((wc * 2 + oth) * 10 + mi * 2 + 0) * 64 + lane];
        f32x4 q1 = part[((wc * 2 + oth) * 10 + mi * 2 + 1) * 64 + lane];
        // add into the OWNED token-half (static indices both arms)
        f32x4 s0 = (hi ? o[mi][2] : o[mi][0]) + q0;
        f32x4 s1 = (hi ? o[mi][3] : o[mi][1]) + q1;
        if (hi) { o[mi][2] = s0; o[mi][3] = s1; }
        else    { o[mi][0] = s0; o[mi][1] = s1; }
    }

    // ---- epilogue: coalesced store + bias + residual (owned token half) ----
    int cw = wc * 80;
    #pragma unroll
    for (int mi = 0; mi < 5; ++mi)
        #pragma unroll
        for (int ntl = 0; ntl < 2; ++ntl) {
            f32x4 val = ntl ? (hi ? o[mi][3] : o[mi][1])
                            : (hi ? o[mi][2] : o[mi][0]);
            int nt = kh * 2 + ntl;   // runtime, but only used in the ADDRESS
            #pragma unroll
            for (int r = 0; r < 4; ++r) {
                int co = cw + mi * 16 + g * 4 + r;
                float bo = bout[co];
                size_t oi = ((size_t)(b * 320 + co)) * 4096 + t0 + nt * 16 + lr;
                out[oi] = val[r] + bo + x[oi];
            }
        }
}

// ---------------- launch ----------------
extern "C" void kernel_launch(void* const* d_in, const int* in_sizes, int n_in,
                              void* d_out, int out_size, void* d_ws, size_t ws_size,
                              hipStream_t stream) {
    const float* x     = (const float*)d_in[0];
    const float* ctx   = (const float*)d_in[1];
    const float* Wq    = (const float*)d_in[2];
    const float* Wk    = (const float*)d_in[3];
    const float* Wv    = (const float*)d_in[4];
    const float* Wout  = (const float*)d_in[5];
    const float* bout  = (const float*)d_in[6];
    const float* gamma = (const float*)d_in[7];
    const float* beta  = (const float*)d_in[8];
    float* out = (float*)d_out;
    char* ws = (char*)d_ws;

    // workspace layout (bytes)
    us* qG    = (us*)(ws);                 // 20971520
    us* kbuf  = (us*)(ws + 20971520);      // 394240
    us* vbuf  = (us*)(ws + 21365760);      // 394240
    us* vwT   = (us*)(ws + 21760000);      // 3276800
    us* vwF   = (us*)(ws + 25036800);      // 3276800
    us* kF    = (us*)(ws + 28313600);      // 655360
    us* wqF   = (us*)(ws + 28968960);      // 204800
    us* WkT   = (us*)(ws + 29173760);      // 491520
    us* WvT   = (us*)(ws + 29665280);      // 491520
    us* WoutT = (us*)(ws + 30156800);      // 204800

    wtrans_all<<<dim3(630), 256, 0, stream>>>(Wq, Wk, Wv, Wout, wqF, WkT, WvT, WoutT);
    gemm_kv<<<dim3(10, 5, 2), 256, 0, stream>>>(ctx, WkT, WvT, kbuf, vbuf);
    gemm_vw<<<dim3(5, 8, 8), 256, 0, stream>>>(WoutT, vbuf, vwT);
    repack_all<<<dim3(960), 256, 0, stream>>>(kbuf, vwT, kF, vwF);
    ln_q_fused<<<dim3(512), 256, 0, stream>>>(x, gamma, beta, wqF, qG);
    attn_out<<<dim3(512), 512, 0, stream>>>(qG, kF, vwF, bout, x, out);
}

// Round 15
// 93.168 us; speedup vs baseline: 1.1611x; 1.1611x over previous
//
#include <hip/hip_runtime.h>

// ---------------- constants ----------------
#define HEADS 8
#define DH 40
constexpr int Bn   = 8;
constexpr int Cc   = 320;
constexpr int Nn   = 4096;        // tokens per batch (64*64)
constexpr int CTX  = 77;
constexpr float LN_EPS = 1e-5f;
constexpr float SCALE  = 0.15811388300841897f; // 40^-0.5

typedef short bf16x8 __attribute__((ext_vector_type(8)));
typedef float f32x4  __attribute__((ext_vector_type(4)));
typedef unsigned short us;

__device__ inline us f2bf(float f) {
    unsigned u = __float_as_uint(f);
    u += 0x7fffu + ((u >> 16) & 1u);
    return (us)(u >> 16);
}
__device__ inline float bf2f(us h) {
    return __uint_as_float(((unsigned)h) << 16);
}

// ---------------- weight prep: transposes (Wk,Wv,Wout) + Wq B-frag pack, one launch ----------------
__global__ __launch_bounds__(256) void wtrans_all(const float* __restrict__ Wq,
                                                  const float* __restrict__ Wk,
                                                  const float* __restrict__ Wv,
                                                  const float* __restrict__ Wout,
                                                  us* __restrict__ wqF,
                                                  us* __restrict__ WkT,
                                                  us* __restrict__ WvT,
                                                  us* __restrict__ WoutT) {
    int id = blockIdx.x;
    if (id >= 580) {
        // Wq -> MFMA B-fragment order: wqF[(ct*10+kc)][lane] = Wq[kc*32+g*8+e][ct*16+lr]
        int wid = (id - 580) * 4 + (threadIdx.x >> 6);  // 0..199
        int lane = threadIdx.x & 63, lr = lane & 15, g = lane >> 4;
        int ct = wid / 10, kc = wid % 10;
        int k0 = kc * 32 + g * 8, co = ct * 16 + lr;
        us tmp[8];
        #pragma unroll
        for (int e = 0; e < 8; ++e)
            tmp[e] = f2bf(Wq[(size_t)(k0 + e) * 320 + co]);
        ((uint4*)wqF)[(size_t)wid * 64 + lane] = *(uint4*)tmp;
        return;
    }
    const float* in; us* out; int K, t;
    if (id < 240)      { in = Wk;   out = WkT;   K = 768; t = id; }
    else if (id < 480) { in = Wv;   out = WvT;   K = 768; t = id - 240; }
    else               { in = Wout; out = WoutT; K = 320; t = id - 480; }
    int ktiles = K >> 5;
    int kb = (t % ktiles) * 32, ob = (t / ktiles) * 32;

    __shared__ float tile[32][33];
    int tx = threadIdx.x & 31, ty = threadIdx.x >> 5; // ty 0..7
    #pragma unroll
    for (int i = 0; i < 32; i += 8)
        tile[ty + i][tx] = in[(size_t)(kb + ty + i) * 320 + ob + tx];
    __syncthreads();
    #pragma unroll
    for (int i = 0; i < 32; i += 8)
        out[(size_t)(ob + ty + i) * K + kb + tx] = f2bf(tile[tx][ty + i]);
}

// ---------------- K/V projection: ctx fp32 [616][768] x W^T -> bf16 [616][320] ----------------
__global__ __launch_bounds__(256) void gemm_kv(const float* __restrict__ ctx,
                                               const us* __restrict__ WkT,
                                               const us* __restrict__ WvT,
                                               us* __restrict__ kbuf,
                                               us* __restrict__ vbuf) {
    const us* Bt = blockIdx.z ? WvT : WkT;
    us* Cm = blockIdx.z ? vbuf : kbuf;
    constexpr int K = 768, M = 616;
    __shared__ __align__(16) char Al[64 * 128];
    __shared__ __align__(16) char Bl[64 * 128];
    int m0 = blockIdx.x * 64;
    int n0 = blockIdx.y * 64;
    int tid = threadIdx.x;
    int lane = tid & 63, wave = tid >> 6;
    int wm = (wave >> 1) * 32, wn = (wave & 1) * 32;

    f32x4 acc[2][2] = {};

    for (int kc = 0; kc < K; kc += 64) {
        #pragma unroll
        for (int i = 0; i < 2; ++i) {
            int chunk = tid + 256 * i;
            int r = chunk >> 3, c8 = chunk & 7;
            int off = (r * 128 + c8 * 16) ^ ((r & 7) << 4);
            int gr = m0 + r;
            uint4 av = make_uint4(0, 0, 0, 0);
            if (gr < M) {
                float4 f0 = *(const float4*)(ctx + (size_t)gr * K + kc + c8 * 8);
                float4 f1 = *(const float4*)(ctx + (size_t)gr * K + kc + c8 * 8 + 4);
                av.x = f2bf(f0.x) | ((unsigned)f2bf(f0.y) << 16);
                av.y = f2bf(f0.z) | ((unsigned)f2bf(f0.w) << 16);
                av.z = f2bf(f1.x) | ((unsigned)f2bf(f1.y) << 16);
                av.w = f2bf(f1.z) | ((unsigned)f2bf(f1.w) << 16);
            }
            *(uint4*)(Al + off) = av;
            *(uint4*)(Bl + off) = *(const uint4*)(Bt + (size_t)(n0 + r) * K + kc + c8 * 8);
        }
        __syncthreads();

        #pragma unroll
        for (int kk = 0; kk < 64; kk += 32) {
            bf16x8 a[2], bfr[2];
            int lr = lane & 15;
            int lkb = (kk + (lane >> 4) * 8) * 2;
            #pragma unroll
            for (int mi = 0; mi < 2; ++mi) {
                int row = wm + mi * 16 + lr;
                a[mi] = *(const bf16x8*)(Al + ((row * 128 + lkb) ^ ((row & 7) << 4)));
            }
            #pragma unroll
            for (int ni = 0; ni < 2; ++ni) {
                int row = wn + ni * 16 + lr;
                bfr[ni] = *(const bf16x8*)(Bl + ((row * 128 + lkb) ^ ((row & 7) << 4)));
            }
            #pragma unroll
            for (int mi = 0; mi < 2; ++mi)
                #pragma unroll
                for (int ni = 0; ni < 2; ++ni)
                    acc[mi][ni] = __builtin_amdgcn_mfma_f32_16x16x32_bf16(a[mi], bfr[ni], acc[mi][ni], 0, 0, 0);
        }
        __syncthreads();
    }

    int lr = lane & 15, lq = lane >> 4;
    #pragma unroll
    for (int mi = 0; mi < 2; ++mi)
        #pragma unroll
        for (int ni = 0; ni < 2; ++ni)
            #pragma unroll
            for (int r = 0; r < 4; ++r) {
                int row = m0 + wm + mi * 16 + lq * 4 + r;
                int col = n0 + wn + ni * 16 + lr;
                if (row < M)
                    Cm[(size_t)row * 320 + col] = f2bf(acc[mi][ni][r]);
            }
}

// ---------------- VW precompute: vwT[b][c][h*80+j] = sum_d Wout[h*40+d][c] * V[b,j,h*40+d] ----------------
__global__ __launch_bounds__(256) void gemm_vw(const us* __restrict__ WoutT,
                                               const us* __restrict__ vbuf,
                                               us* __restrict__ vwT) {
    int b = blockIdx.z, h = blockIdx.y, cb = blockIdx.x * 64;
    int tid = threadIdx.x, lane = tid & 63, w = tid >> 6;
    int lr = lane & 15, g = lane >> 4;

    int crow = cb + w * 16 + lr;
    const us* ab = WoutT + (size_t)crow * 320 + h * DH;
    bf16x8 a0 = *(const bf16x8*)(ab + g * 8);
    bf16x8 a1 = {};
    if (g == 0) a1 = *(const bf16x8*)(ab + 32);

    f32x4 acc[5] = {};
    #pragma unroll
    for (int nt = 0; nt < 5; ++nt) {
        int j = nt * 16 + lr;
        bool jv = j < CTX;
        const us* kr = vbuf + (size_t)(b * CTX + (jv ? j : 0)) * 320 + h * DH;
        bf16x8 b0 = {}, b1 = {};
        if (jv) b0 = *(const bf16x8*)(kr + g * 8);
        if (jv && g == 0) b1 = *(const bf16x8*)(kr + 32);
        acc[nt] = __builtin_amdgcn_mfma_f32_16x16x32_bf16(a0, b0, acc[nt], 0, 0, 0);
        acc[nt] = __builtin_amdgcn_mfma_f32_16x16x32_bf16(a1, b1, acc[nt], 0, 0, 0);
    }

    #pragma unroll
    for (int nt = 0; nt < 5; ++nt)
        #pragma unroll
        for (int r = 0; r < 4; ++r) {
            int c = cb + w * 16 + g * 4 + r;
            float val = (nt == 4 && lr >= 13) ? 0.f : acc[nt][r];
            vwT[((size_t)(b * 320 + c)) * 640 + h * 80 + nt * 16 + lr] = f2bf(val);
        }
}

// ---------------- merged: repack K+VW (blocks 0..959) + LN+Qproj (blocks 960..1471) ----------------
__global__ __launch_bounds__(256, 3) void prep_ln(const us* __restrict__ kbuf,
                                                  const us* __restrict__ vwT,
                                                  us* __restrict__ kF,
                                                  us* __restrict__ vwF,
                                                  const float* __restrict__ x,
                                                  const float* __restrict__ gamma,
                                                  const float* __restrict__ beta,
                                                  const us* __restrict__ wqF,
                                                  us* __restrict__ qG) {
    __shared__ __align__(16) us xnt[64 * 328];
    __shared__ float red1[4][64], red2[4][64];
    __shared__ float mu_s[64], rs_s[64];

    int id = blockIdx.x;
    int lane = threadIdx.x & 63, lr = lane & 15, g = lane >> 4;

    if (id < 160) {
        int wid = id * 4 + (threadIdx.x >> 6);       // 0..639
        int kc = wid & 1, nt = (wid >> 1) % 5, h = (wid / 10) & 7, b = wid / 80;
        int j = nt * 16 + lr, d0 = kc * 32 + g * 8;
        bf16x8 v = {};
        if (j < CTX && d0 < DH)
            v = *(const bf16x8*)(kbuf + ((size_t)(b * CTX + j)) * 320 + h * DH + d0);
        ((bf16x8*)kF)[(size_t)wid * 64 + lane] = v;
        return;
    }
    if (id < 960) {
        int wid = (id - 160) * 4 + (threadIdx.x >> 6);   // 0..3199
        int mi = wid % 5, ks = (wid / 5) % 20, w = (wid / 100) & 3, b = wid / 400;
        int co = w * 80 + mi * 16 + lr, k = ks * 32 + g * 8;
        bf16x8 v = *(const bf16x8*)(vwT + ((size_t)(b * 320 + co)) * 640 + k);
        ((bf16x8*)vwF)[(size_t)wid * 64 + lane] = v;
        return;
    }

    // ---- LN + Q projection ----
    int lbid = id - 960;                 // 0..511
    int b  = lbid >> 6;
    int t0 = (lbid & 63) * 64;
    int tid = threadIdx.x;
    int tl = tid & 63, cg = tid >> 6;
    const float* xb = x + (size_t)b * Cc * Nn + t0 + tl;

    float s1 = 0.f, s2 = 0.f;
    #pragma unroll 8
    for (int i = 0; i < 80; ++i) {
        int c = cg * 80 + i;
        float v = xb[(size_t)c * Nn];
        s1 += v; s2 += v * v;
        xnt[tl * 328 + c] = f2bf(v);
    }
    red1[cg][tl] = s1; red2[cg][tl] = s2;
    __syncthreads();
    if (tid < 64) {
        float a1 = red1[0][tl] + red1[1][tl] + red1[2][tl] + red1[3][tl];
        float a2 = red2[0][tl] + red2[1][tl] + red2[2][tl] + red2[3][tl];
        float mu = a1 * (1.0f / Cc);
        float var = a2 * (1.0f / Cc) - mu * mu;
        mu_s[tl] = mu; rs_s[tl] = rsqrtf(var + LN_EPS);
    }
    __syncthreads();
    float mu = mu_s[tl], rs = rs_s[tl];
    #pragma unroll 4
    for (int i = 0; i < 40; ++i) {
        int c = cg * 80 + i * 2;
        unsigned u = *(unsigned*)&xnt[tl * 328 + c];
        float v0 = bf2f((us)(u & 0xffff));
        float v1 = bf2f((us)(u >> 16));
        unsigned lo = f2bf((v0 - mu) * rs * gamma[c]     + beta[c]);
        unsigned hi = f2bf((v1 - mu) * rs * gamma[c + 1] + beta[c + 1]);
        *(unsigned*)&xnt[tl * 328 + c] = lo | (hi << 16);
    }
    __syncthreads();

    int w = tid >> 6;
    f32x4 acc[4][5] = {};   // [token-tile][out-tile]
    const bf16x8* wq = (const bf16x8*)wqF;
    for (int kc = 0; kc < 10; ++kc) {
        bf16x8 bfr[5];
        #pragma unroll
        for (int nt = 0; nt < 5; ++nt)
            bfr[nt] = wq[(size_t)((w * 5 + nt) * 10 + kc) * 64 + lane];
        bf16x8 afr[4];
        #pragma unroll
        for (int mt = 0; mt < 4; ++mt)
            afr[mt] = *(const bf16x8*)&xnt[(mt * 16 + lr) * 328 + kc * 32 + g * 8];
        #pragma unroll
        for (int mt = 0; mt < 4; ++mt)
            #pragma unroll
            for (int nt = 0; nt < 5; ++nt)
                acc[mt][nt] = __builtin_amdgcn_mfma_f32_16x16x32_bf16(afr[mt], bfr[nt], acc[mt][nt], 0, 0, 0);
    }
    __syncthreads();   // xnt consumed; reuse as q-tile [64 tok][320 co]

    #pragma unroll
    for (int mt = 0; mt < 4; ++mt)
        #pragma unroll
        for (int nt = 0; nt < 5; ++nt)
            #pragma unroll
            for (int r = 0; r < 4; ++r)
                xnt[(mt * 16 + g * 4 + r) * 328 + w * 80 + nt * 16 + lr] = f2bf(acc[mt][nt][r]);
    __syncthreads();

    // emit 40 dense fragment blobs (4 tiles x 10 k-frags), 16B/lane coalesced
    size_t gtb = (size_t)b * 256 + (lbid & 63) * 4;
    #pragma unroll
    for (int it = 0; it < 10; ++it) {
        int f_lin = it * 4 + w;            // 0..39
        int tile = f_lin / 10, f = f_lin % 10;
        uint4 v = *(uint4*)&xnt[(tile * 16 + lr) * 328 + f * 32 + g * 8];
        ((uint4*)qG)[((gtb + tile) * 10 + f) * 64 + lane] = v;
    }
}

// ---------------- fused attention + out-proj: 512 threads, 64 tokens/block, single pass (r8) ----------------
// 8 waves: QK^T+softmax with wave=head (P -> [64][640] LDS, 80 KB), one barrier,
// PV with wave=(co-slice 80, token-half 32), K=640 over vwF frags. Epilogue coalesced.
__global__ __launch_bounds__(512, 4) void attn_out(const us* __restrict__ qG,
                                                   const us* __restrict__ kF,
                                                   const us* __restrict__ vwF,
                                                   const float* __restrict__ bout,
                                                   const float* __restrict__ x,
                                                   float* __restrict__ out) {
    __shared__ __align__(16) char Pl[64 * 1280];   // P bf16 [64][640], swizzled (80 KB)

    int bid = blockIdx.x;
    int b = bid & 7, ts = bid >> 3;       // XCD-local batch
    int t0 = ts * 64;
    int tid = threadIdx.x, lane = tid & 63, w = tid >> 6;   // w 0..7
    int lr = lane & 15, g = lane >> 4;

    const bf16x8* qfb = (const bf16x8*)qG;
    const bf16x8* kfb = (const bf16x8*)kF;

    // ---- QK^T + softmax: wave w = head w ----
    {
        int h = w;
        size_t kfh = (size_t)((b * 8 + h) * 10) * 64;
        bf16x8 kb0[5], kb1[5];
        #pragma unroll
        for (int nt = 0; nt < 5; ++nt) {
            kb0[nt] = kfb[kfh + (nt * 2 + 0) * 64 + lane];
            kb1[nt] = kfb[kfh + (nt * 2 + 1) * 64 + lane];
        }
        // dense qG gather: k = 40h + 8g + e  ->  frag (5h+g)>>2, lane ((5h+g)&3)*16+lr
        int f0 = (5 * h + g) >> 2, l0 = ((5 * h + g) & 3) * 16 + lr;
        int f1 = (5 * h + 4) >> 2, l1 = ((5 * h + 4) & 3) * 16 + lr;

        #pragma unroll
        for (int mt = 0; mt < 4; ++mt) {
            const bf16x8* qt = qfb + (size_t)(b * 256 + ts * 4 + mt) * 640;
            bf16x8 a0 = qt[f0 * 64 + l0];
            bf16x8 a1 = {};
            if (g == 0) a1 = qt[f1 * 64 + l1];

            f32x4 S[5] = {};
            #pragma unroll
            for (int nt = 0; nt < 5; ++nt) {
                S[nt] = __builtin_amdgcn_mfma_f32_16x16x32_bf16(a0, kb0[nt], S[nt], 0, 0, 0);
                S[nt] = __builtin_amdgcn_mfma_f32_16x16x32_bf16(a1, kb1[nt], S[nt], 0, 0, 0);
            }

            float pv[5][4];
            #pragma unroll
            for (int nt = 0; nt < 5; ++nt)
                #pragma unroll
                for (int r = 0; r < 4; ++r)
                    pv[nt][r] = (nt == 4 && lr >= 13) ? 0.f : __expf(S[nt][r] * SCALE);
            #pragma unroll
            for (int r = 0; r < 4; ++r) {
                float su = pv[0][r] + pv[1][r] + pv[2][r] + pv[3][r] + pv[4][r];
                #pragma unroll
                for (int off = 1; off < 16; off <<= 1)
                    su += __shfl_xor(su, off);
                float inv = 1.0f / su;
                int row = mt * 16 + g * 4 + r;
                #pragma unroll
                for (int nt = 0; nt < 5; ++nt)
                    *(us*)(Pl + ((row * 1280 + (h * 80 + nt * 16 + lr) * 2) ^ ((row & 7) << 4))) =
                        f2bf(pv[nt][r] * inv);
            }
        }
    }
    __syncthreads();

    // ---- PV: out^T = VW^T @ P^T, K=640; wave -> (wc = co-slice, wt = token-half) ----
    int wc = w >> 1, wt = w & 1;
    f32x4 o[5][2] = {};
    const bf16x8* vwb = (const bf16x8*)vwF + (size_t)((b * 4 + wc) * 100) * 64 + lane;
    __builtin_amdgcn_s_setprio(1);
    #pragma unroll 2
    for (int ks = 0; ks < 20; ++ks) {
        bf16x8 av[5];
        #pragma unroll
        for (int mi = 0; mi < 5; ++mi)
            av[mi] = vwb[(ks * 5 + mi) * 64];
        bf16x8 pb[2];
        #pragma unroll
        for (int nt = 0; nt < 2; ++nt) {
            int row = wt * 32 + nt * 16 + lr;
            pb[nt] = *(const bf16x8*)(Pl + ((row * 1280 + ks * 64 + g * 16) ^ ((row & 7) << 4)));
        }
        #pragma unroll
        for (int mi = 0; mi < 5; ++mi)
            #pragma unroll
            for (int nt = 0; nt < 2; ++nt)
                o[mi][nt] = __builtin_amdgcn_mfma_f32_16x16x32_bf16(av[mi], pb[nt], o[mi][nt], 0, 0, 0);
    }
    __builtin_amdgcn_s_setprio(0);

    // ---- epilogue: coalesced store + bias + residual ----
    int cw = wc * 80;
    #pragma unroll
    for (int mi = 0; mi < 5; ++mi)
        #pragma unroll
        for (int r = 0; r < 4; ++r) {
            int co = cw + mi * 16 + g * 4 + r;
            float bo = bout[co];
            #pragma unroll
            for (int nt = 0; nt < 2; ++nt) {
                size_t oi = ((size_t)(b * 320 + co)) * 4096 + t0 + wt * 32 + nt * 16 + lr;
                out[oi] = o[mi][nt][r] + bo + x[oi];
            }
        }
}

// ---------------- launch ----------------
extern "C" void kernel_launch(void* const* d_in, const int* in_sizes, int n_in,
                              void* d_out, int out_size, void* d_ws, size_t ws_size,
                              hipStream_t stream) {
    const float* x     = (const float*)d_in[0];
    const float* ctx   = (const float*)d_in[1];
    const float* Wq    = (const float*)d_in[2];
    const float* Wk    = (const float*)d_in[3];
    const float* Wv    = (const float*)d_in[4];
    const float* Wout  = (const float*)d_in[5];
    const float* bout  = (const float*)d_in[6];
    const float* gamma = (const float*)d_in[7];
    const float* beta  = (const float*)d_in[8];
    float* out = (float*)d_out;
    char* ws = (char*)d_ws;

    // workspace layout (bytes)
    us* qG    = (us*)(ws);                 // 20971520
    us* kbuf  = (us*)(ws + 20971520);      // 394240
    us* vbuf  = (us*)(ws + 21365760);      // 394240
    us* vwT   = (us*)(ws + 21760000);      // 3276800
    us* vwF   = (us*)(ws + 25036800);      // 3276800
    us* kF    = (us*)(ws + 28313600);      // 655360
    us* wqF   = (us*)(ws + 28968960);      // 204800
    us* WkT   = (us*)(ws + 29173760);      // 491520
    us* WvT   = (us*)(ws + 29665280);      // 491520
    us* WoutT = (us*)(ws + 30156800);      // 204800

    wtrans_all<<<dim3(630), 256, 0, stream>>>(Wq, Wk, Wv, Wout, wqF, WkT, WvT, WoutT);
    gemm_kv<<<dim3(10, 5, 2), 256, 0, stream>>>(ctx, WkT, WvT, kbuf, vbuf);
    gemm_vw<<<dim3(5, 8, 8), 256, 0, stream>>>(WoutT, vbuf, vwT);
    prep_ln<<<dim3(1472), 256, 0, stream>>>(kbuf, vwT, kF, vwF, x, gamma, beta, wqF, qG);
    attn_out<<<dim3(512), 512, 0, stream>>>(qG, kF, vwF, bout, x, out);
}

// Round 16
// 92.840 us; speedup vs baseline: 1.1652x; 1.0035x over previous
//
#include <hip/hip_runtime.h>

// ---------------- constants ----------------
#define HEADS 8
#define DH 40
constexpr int Bn   = 8;
constexpr int Cc   = 320;
constexpr int Nn   = 4096;        // tokens per batch (64*64)
constexpr int CTX  = 77;
constexpr float LN_EPS = 1e-5f;
constexpr float SCALE  = 0.15811388300841897f; // 40^-0.5

typedef short bf16x8 __attribute__((ext_vector_type(8)));
typedef float f32x4  __attribute__((ext_vector_type(4)));
typedef unsigned short us;

__device__ inline us f2bf(float f) {
    unsigned u = __float_as_uint(f);
    u += 0x7fffu + ((u >> 16) & 1u);
    return (us)(u >> 16);
}
__device__ inline float bf2f(us h) {
    return __uint_as_float(((unsigned)h) << 16);
}

// ---------------- weight prep: transposes (Wk,Wv,Wout) + Wq B-frag pack, one launch ----------------
__global__ __launch_bounds__(256) void wtrans_all(const float* __restrict__ Wq,
                                                  const float* __restrict__ Wk,
                                                  const float* __restrict__ Wv,
                                                  const float* __restrict__ Wout,
                                                  us* __restrict__ wqF,
                                                  us* __restrict__ WkT,
                                                  us* __restrict__ WvT,
                                                  us* __restrict__ WoutT) {
    int id = blockIdx.x;
    if (id >= 580) {
        // Wq -> MFMA B-fragment order: wqF[(ct*10+kc)][lane] = Wq[kc*32+g*8+e][ct*16+lr]
        int wid = (id - 580) * 4 + (threadIdx.x >> 6);  // 0..199
        int lane = threadIdx.x & 63, lr = lane & 15, g = lane >> 4;
        int ct = wid / 10, kc = wid % 10;
        int k0 = kc * 32 + g * 8, co = ct * 16 + lr;
        us tmp[8];
        #pragma unroll
        for (int e = 0; e < 8; ++e)
            tmp[e] = f2bf(Wq[(size_t)(k0 + e) * 320 + co]);
        ((uint4*)wqF)[(size_t)wid * 64 + lane] = *(uint4*)tmp;
        return;
    }
    const float* in; us* out; int K, t;
    if (id < 240)      { in = Wk;   out = WkT;   K = 768; t = id; }
    else if (id < 480) { in = Wv;   out = WvT;   K = 768; t = id - 240; }
    else               { in = Wout; out = WoutT; K = 320; t = id - 480; }
    int ktiles = K >> 5;
    int kb = (t % ktiles) * 32, ob = (t / ktiles) * 32;

    __shared__ float tile[32][33];
    int tx = threadIdx.x & 31, ty = threadIdx.x >> 5; // ty 0..7
    #pragma unroll
    for (int i = 0; i < 32; i += 8)
        tile[ty + i][tx] = in[(size_t)(kb + ty + i) * 320 + ob + tx];
    __syncthreads();
    #pragma unroll
    for (int i = 0; i < 32; i += 8)
        out[(size_t)(ob + ty + i) * K + kb + tx] = f2bf(tile[tx][ty + i]);
}

// ---------------- K/V projection: ctx fp32 [616][768] x W^T -> bf16 [616][320] ----------------
__global__ __launch_bounds__(256) void gemm_kv(const float* __restrict__ ctx,
                                               const us* __restrict__ WkT,
                                               const us* __restrict__ WvT,
                                               us* __restrict__ kbuf,
                                               us* __restrict__ vbuf) {
    const us* Bt = blockIdx.z ? WvT : WkT;
    us* Cm = blockIdx.z ? vbuf : kbuf;
    constexpr int K = 768, M = 616;
    __shared__ __align__(16) char Al[64 * 128];
    __shared__ __align__(16) char Bl[64 * 128];
    int m0 = blockIdx.x * 64;
    int n0 = blockIdx.y * 64;
    int tid = threadIdx.x;
    int lane = tid & 63, wave = tid >> 6;
    int wm = (wave >> 1) * 32, wn = (wave & 1) * 32;

    f32x4 acc[2][2] = {};

    for (int kc = 0; kc < K; kc += 64) {
        #pragma unroll
        for (int i = 0; i < 2; ++i) {
            int chunk = tid + 256 * i;
            int r = chunk >> 3, c8 = chunk & 7;
            int off = (r * 128 + c8 * 16) ^ ((r & 7) << 4);
            int gr = m0 + r;
            uint4 av = make_uint4(0, 0, 0, 0);
            if (gr < M) {
                float4 f0 = *(const float4*)(ctx + (size_t)gr * K + kc + c8 * 8);
                float4 f1 = *(const float4*)(ctx + (size_t)gr * K + kc + c8 * 8 + 4);
                av.x = f2bf(f0.x) | ((unsigned)f2bf(f0.y) << 16);
                av.y = f2bf(f0.z) | ((unsigned)f2bf(f0.w) << 16);
                av.z = f2bf(f1.x) | ((unsigned)f2bf(f1.y) << 16);
                av.w = f2bf(f1.z) | ((unsigned)f2bf(f1.w) << 16);
            }
            *(uint4*)(Al + off) = av;
            *(uint4*)(Bl + off) = *(const uint4*)(Bt + (size_t)(n0 + r) * K + kc + c8 * 8);
        }
        __syncthreads();

        #pragma unroll
        for (int kk = 0; kk < 64; kk += 32) {
            bf16x8 a[2], bfr[2];
            int lr = lane & 15;
            int lkb = (kk + (lane >> 4) * 8) * 2;
            #pragma unroll
            for (int mi = 0; mi < 2; ++mi) {
                int row = wm + mi * 16 + lr;
                a[mi] = *(const bf16x8*)(Al + ((row * 128 + lkb) ^ ((row & 7) << 4)));
            }
            #pragma unroll
            for (int ni = 0; ni < 2; ++ni) {
                int row = wn + ni * 16 + lr;
                bfr[ni] = *(const bf16x8*)(Bl + ((row * 128 + lkb) ^ ((row & 7) << 4)));
            }
            #pragma unroll
            for (int mi = 0; mi < 2; ++mi)
                #pragma unroll
                for (int ni = 0; ni < 2; ++ni)
                    acc[mi][ni] = __builtin_amdgcn_mfma_f32_16x16x32_bf16(a[mi], bfr[ni], acc[mi][ni], 0, 0, 0);
        }
        __syncthreads();
    }

    int lr = lane & 15, lq = lane >> 4;
    #pragma unroll
    for (int mi = 0; mi < 2; ++mi)
        #pragma unroll
        for (int ni = 0; ni < 2; ++ni)
            #pragma unroll
            for (int r = 0; r < 4; ++r) {
                int row = m0 + wm + mi * 16 + lq * 4 + r;
                int col = n0 + wn + ni * 16 + lr;
                if (row < M)
                    Cm[(size_t)row * 320 + col] = f2bf(acc[mi][ni][r]);
            }
}

// ---------------- VW precompute: vwT[b][c][h*80+j] = sum_d Wout[h*40+d][c] * V[b,j,h*40+d] ----------------
__global__ __launch_bounds__(256) void gemm_vw(const us* __restrict__ WoutT,
                                               const us* __restrict__ vbuf,
                                               us* __restrict__ vwT) {
    int b = blockIdx.z, h = blockIdx.y, cb = blockIdx.x * 64;
    int tid = threadIdx.x, lane = tid & 63, w = tid >> 6;
    int lr = lane & 15, g = lane >> 4;

    int crow = cb + w * 16 + lr;
    const us* ab = WoutT + (size_t)crow * 320 + h * DH;
    bf16x8 a0 = *(const bf16x8*)(ab + g * 8);
    bf16x8 a1 = {};
    if (g == 0) a1 = *(const bf16x8*)(ab + 32);

    f32x4 acc[5] = {};
    #pragma unroll
    for (int nt = 0; nt < 5; ++nt) {
        int j = nt * 16 + lr;
        bool jv = j < CTX;
        const us* kr = vbuf + (size_t)(b * CTX + (jv ? j : 0)) * 320 + h * DH;
        bf16x8 b0 = {}, b1 = {};
        if (jv) b0 = *(const bf16x8*)(kr + g * 8);
        if (jv && g == 0) b1 = *(const bf16x8*)(kr + 32);
        acc[nt] = __builtin_amdgcn_mfma_f32_16x16x32_bf16(a0, b0, acc[nt], 0, 0, 0);
        acc[nt] = __builtin_amdgcn_mfma_f32_16x16x32_bf16(a1, b1, acc[nt], 0, 0, 0);
    }

    #pragma unroll
    for (int nt = 0; nt < 5; ++nt)
        #pragma unroll
        for (int r = 0; r < 4; ++r) {
            int c = cb + w * 16 + g * 4 + r;
            float val = (nt == 4 && lr >= 13) ? 0.f : acc[nt][r];
            vwT[((size_t)(b * 320 + c)) * 640 + h * 80 + nt * 16 + lr] = f2bf(val);
        }
}

// ---------------- repack K + VW into MFMA-fragment order, one launch ----------------
__global__ __launch_bounds__(256) void repack_all(const us* __restrict__ kbuf,
                                                  const us* __restrict__ vwT,
                                                  us* __restrict__ kF,
                                                  us* __restrict__ vwF) {
    int id = blockIdx.x;
    int lane = threadIdx.x & 63, lr = lane & 15, g = lane >> 4;
    if (id < 160) {
        int wid = id * 4 + (threadIdx.x >> 6);       // 0..639
        int kc = wid & 1, nt = (wid >> 1) % 5, h = (wid / 10) & 7, b = wid / 80;
        int j = nt * 16 + lr, d0 = kc * 32 + g * 8;
        bf16x8 v = {};
        if (j < CTX && d0 < DH)
            v = *(const bf16x8*)(kbuf + ((size_t)(b * CTX + j)) * 320 + h * DH + d0);
        ((bf16x8*)kF)[(size_t)wid * 64 + lane] = v;
    } else {
        int wid = (id - 160) * 4 + (threadIdx.x >> 6);   // 0..3199
        int mi = wid % 5, ks = (wid / 5) % 20, w = (wid / 100) & 3, b = wid / 400;
        int co = w * 80 + mi * 16 + lr, k = ks * 32 + g * 8;
        bf16x8 v = *(const bf16x8*)(vwT + ((size_t)(b * 320 + co)) * 640 + k);
        ((bf16x8*)vwF)[(size_t)wid * 64 + lane] = v;
    }
}

// ---------------- fully fused: LN + Qproj + attention + out-proj + residual ----------------
// 512 blocks (b=bid&7 XCD-local, 64 tokens), 512 threads.
// LDS = two DISJOINT 40KB halves (no aliasing races):
//   xs @0     : x->xnorm [64][320] bf16 swz; reused as P-half [64][320] after Qproj.
//   q  @40960 : red/mu (phases 1-2 only), then q [64][320] bf16 swz.
// Heads split in two passes (ph=0: h0..3, ph=1: h4..7); PV accumulates o[5][2] across both.
__global__ __launch_bounds__(512, 4) void fused_attn(const float* __restrict__ x,
                                                     const float* __restrict__ gamma,
                                                     const float* __restrict__ beta,
                                                     const us* __restrict__ wqF,
                                                     const us* __restrict__ kF,
                                                     const us* __restrict__ vwF,
                                                     const float* __restrict__ bout,
                                                     float* __restrict__ out) {
    __shared__ __align__(16) char smem[81920];
    char* xsq = smem;                                 // [64][320] bf16 swz: xnorm, then P-half
    char* qls = smem + 40960;                         // [64][320] bf16 swz: q
    float* red1 = (float*)(smem + 40960);             // [8][64] (dead before q written)
    float* red2 = (float*)(smem + 40960 + 2048);
    float* mu_s = (float*)(smem + 40960 + 4096);
    float* rs_s = (float*)(smem + 40960 + 4352);

    int bid = blockIdx.x;
    int b = bid & 7, ts = bid >> 3;
    int t0 = ts * 64;
    int tid = threadIdx.x, lane = tid & 63, w = tid >> 6;
    int lr = lane & 15, g = lane >> 4;
    int tl = tid & 63, cg = tid >> 6;

    // ---- phase 1: load x once + LN stats (bf16 staged to xs) ----
    const float* xb = x + (size_t)b * Cc * Nn + t0 + tl;
    int xswz = (tl & 7) << 4;
    float s1 = 0.f, s2 = 0.f;
    #pragma unroll
    for (int j = 0; j < 20; ++j) {
        int c = cg * 40 + j * 2;
        float v0 = xb[(size_t)c * Nn];
        float v1 = xb[(size_t)(c + 1) * Nn];
        s1 += v0 + v1; s2 += v0 * v0 + v1 * v1;
        *(unsigned*)(xsq + ((tl * 640 + c * 2) ^ xswz)) =
            (unsigned)f2bf(v0) | ((unsigned)f2bf(v1) << 16);
    }
    red1[cg * 64 + tl] = s1; red2[cg * 64 + tl] = s2;
    __syncthreads();
    if (tid < 64) {
        float a1 = 0.f, a2 = 0.f;
        #pragma unroll
        for (int k = 0; k < 8; ++k) { a1 += red1[k * 64 + tid]; a2 += red2[k * 64 + tid]; }
        float mu = a1 * (1.f / Cc);
        float var = a2 * (1.f / Cc) - mu * mu;
        mu_s[tid] = mu; rs_s[tid] = rsqrtf(var + LN_EPS);
    }
    __syncthreads();

    // ---- phase 2: normalize in place ----
    {
        float mu = mu_s[tl], rs = rs_s[tl];
        #pragma unroll
        for (int j = 0; j < 20; ++j) {
            int c = cg * 40 + j * 2;
            unsigned* p = (unsigned*)(xsq + ((tl * 640 + c * 2) ^ xswz));
            unsigned u = *p;
            float v0 = bf2f((us)(u & 0xffff)), v1 = bf2f((us)(u >> 16));
            unsigned lo = f2bf((v0 - mu) * rs * gamma[c]     + beta[c]);
            unsigned hi = f2bf((v1 - mu) * rs * gamma[c + 1] + beta[c + 1]);
            *p = lo | (hi << 16);
        }
    }
    __syncthreads();

    // ---- phase 3: Qproj. wave = (mq = mt-pair, cq = co-quarter of 80) ----
    {
        int mq = w & 1, cq = w >> 1;
        f32x4 acc[2][5] = {};
        const bf16x8* wq = (const bf16x8*)wqF;
        for (int kc = 0; kc < 10; ++kc) {
            bf16x8 bfr[5];
            #pragma unroll
            for (int nt = 0; nt < 5; ++nt)
                bfr[nt] = wq[(size_t)((cq * 5 + nt) * 10 + kc) * 64 + lane];
            bf16x8 afr[2];
            #pragma unroll
            for (int m = 0; m < 2; ++m) {
                int row = (mq * 2 + m) * 16 + lr;
                afr[m] = *(const bf16x8*)(xsq + ((row * 640 + kc * 64 + g * 16) ^ ((row & 7) << 4)));
            }
            #pragma unroll
            for (int m = 0; m < 2; ++m)
                #pragma unroll
                for (int nt = 0; nt < 5; ++nt)
                    acc[m][nt] = __builtin_amdgcn_mfma_f32_16x16x32_bf16(afr[m], bfr[nt], acc[m][nt], 0, 0, 0);
        }
        // C-layout -> q LDS (disjoint region; red/mu dead)
        #pragma unroll
        for (int m = 0; m < 2; ++m)
            #pragma unroll
            for (int nt = 0; nt < 5; ++nt)
                #pragma unroll
                for (int r = 0; r < 4; ++r) {
                    int row = (mq * 2 + m) * 16 + g * 4 + r;
                    int col = cq * 80 + nt * 16 + lr;
                    *(us*)(qls + ((row * 640 + col * 2) ^ ((row & 7) << 4))) = f2bf(acc[m][nt][r]);
                }
    }
    __syncthreads();

    // ---- phases 4-5: attention in two head-halves ----
    const bf16x8* kfb = (const bf16x8*)kF;
    f32x4 o[5][2] = {};
    int wc = w >> 1, wt = w & 1;      // PV roles
    int hh2 = w >> 1, mqk = w & 1;    // QK roles
    #pragma unroll
    for (int ph = 0; ph < 2; ++ph) {
        // QK^T + softmax: head h = ph*4+hh2, token tiles mt = 2*mqk..2*mqk+1
        int h = ph * 4 + hh2;
        size_t kfh = (size_t)((b * 8 + h) * 10) * 64;
        #pragma unroll
        for (int m = 0; m < 2; ++m) {
            int mt = mqk * 2 + m;
            int arow = mt * 16 + lr;
            bf16x8 a0 = *(const bf16x8*)(qls + ((arow * 640 + h * 80 + g * 16) ^ ((arow & 7) << 4)));
            bf16x8 a1 = {};
            if (g == 0)
                a1 = *(const bf16x8*)(qls + ((arow * 640 + h * 80 + 64) ^ ((arow & 7) << 4)));

            f32x4 S[5] = {};
            #pragma unroll
            for (int nt = 0; nt < 5; ++nt) {
                bf16x8 kb0 = kfb[kfh + (nt * 2 + 0) * 64 + lane];
                bf16x8 kb1 = kfb[kfh + (nt * 2 + 1) * 64 + lane];
                S[nt] = __builtin_amdgcn_mfma_f32_16x16x32_bf16(a0, kb0, S[nt], 0, 0, 0);
                S[nt] = __builtin_amdgcn_mfma_f32_16x16x32_bf16(a1, kb1, S[nt], 0, 0, 0);
            }

            float pv[5][4];
            #pragma unroll
            for (int nt = 0; nt < 5; ++nt)
                #pragma unroll
                for (int r = 0; r < 4; ++r)
                    pv[nt][r] = (nt == 4 && lr >= 13) ? 0.f : __expf(S[nt][r] * SCALE);
            #pragma unroll
            for (int r = 0; r < 4; ++r) {
                float su = pv[0][r] + pv[1][r] + pv[2][r] + pv[3][r] + pv[4][r];
                #pragma unroll
                for (int off = 1; off < 16; off <<= 1)
                    su += __shfl_xor(su, off);
                float inv = 1.0f / su;
                int row = mt * 16 + g * 4 + r;
                #pragma unroll
                for (int nt = 0; nt < 5; ++nt)
                    *(us*)(xsq + ((row * 640 + ((h & 3) * 80 + nt * 16 + lr) * 2) ^ ((row & 7) << 4))) =
                        f2bf(pv[nt][r] * inv);
            }
        }
        __syncthreads();

        // PV: o += VW[:, ph-half] @ P^T; wave = (wc co-slice 80, wt token-half 32)
        const bf16x8* vwb = (const bf16x8*)vwF + (size_t)((b * 4 + wc) * 100 + ph * 50) * 64 + lane;
        __builtin_amdgcn_s_setprio(1);
        #pragma unroll 2
        for (int ks = 0; ks < 10; ++ks) {
            bf16x8 av[5];
            #pragma unroll
            for (int mi = 0; mi < 5; ++mi)
                av[mi] = vwb[(ks * 5 + mi) * 64];
            bf16x8 pb[2];
            #pragma unroll
            for (int nt2 = 0; nt2 < 2; ++nt2) {
                int row = wt * 32 + nt2 * 16 + lr;
                pb[nt2] = *(const bf16x8*)(xsq + ((row * 640 + ks * 64 + g * 16) ^ ((row & 7) << 4)));
            }
            #pragma unroll
            for (int mi = 0; mi < 5; ++mi)
                #pragma unroll
                for (int nt2 = 0; nt2 < 2; ++nt2)
                    o[mi][nt2] = __builtin_amdgcn_mfma_f32_16x16x32_bf16(av[mi], pb[nt2], o[mi][nt2], 0, 0, 0);
        }
        __builtin_amdgcn_s_setprio(0);
        __syncthreads();   // P rewritten next ph
    }

    // ---- epilogue: coalesced [b,c,n] store + bias + residual (x L2-hot from phase 1) ----
    int cw = wc * 80;
    #pragma unroll
    for (int mi = 0; mi < 5; ++mi)
        #pragma unroll
        for (int r = 0; r < 4; ++r) {
            int co = cw + mi * 16 + g * 4 + r;
            float bo = bout[co];
            #pragma unroll
            for (int nt2 = 0; nt2 < 2; ++nt2) {
                size_t oi = ((size_t)(b * 320 + co)) * 4096 + t0 + wt * 32 + nt2 * 16 + lr;
                out[oi] = o[mi][nt2][r] + bo + x[oi];
            }
        }
}

// ---------------- launch ----------------
extern "C" void kernel_launch(void* const* d_in, const int* in_sizes, int n_in,
                              void* d_out, int out_size, void* d_ws, size_t ws_size,
                              hipStream_t stream) {
    const float* x     = (const float*)d_in[0];
    const float* ctx   = (const float*)d_in[1];
    const float* Wq    = (const float*)d_in[2];
    const float* Wk    = (const float*)d_in[3];
    const float* Wv    = (const float*)d_in[4];
    const float* Wout  = (const float*)d_in[5];
    const float* bout  = (const float*)d_in[6];
    const float* gamma = (const float*)d_in[7];
    const float* beta  = (const float*)d_in[8];
    float* out = (float*)d_out;
    char* ws = (char*)d_ws;

    // workspace layout (bytes)
    us* kbuf  = (us*)(ws);                 // 394240
    us* vbuf  = (us*)(ws + 394240);        // 394240
    us* vwT   = (us*)(ws + 788480);        // 3276800
    us* vwF   = (us*)(ws + 4065280);       // 3276800
    us* kF    = (us*)(ws + 7342080);       // 655360
    us* wqF   = (us*)(ws + 7997440);       // 204800
    us* WkT   = (us*)(ws + 8202240);       // 491520
    us* WvT   = (us*)(ws + 8693760);       // 491520
    us* WoutT = (us*)(ws + 9185280);       // 204800

    wtrans_all<<<dim3(630), 256, 0, stream>>>(Wq, Wk, Wv, Wout, wqF, WkT, WvT, WoutT);
    gemm_kv<<<dim3(10, 5, 2), 256, 0, stream>>>(ctx, WkT, WvT, kbuf, vbuf);
    gemm_vw<<<dim3(5, 8, 8), 256, 0, stream>>>(WoutT, vbuf, vwT);
    repack_all<<<dim3(960), 256, 0, stream>>>(kbuf, vwT, kF, vwF);
    fused_attn<<<dim3(512), 512, 0, stream>>>(x, gamma, beta, wqF, kF, vwF, bout, out);
}